// Round 13
// baseline (259.611 us; speedup 1.0000x reference)
//
#include <hip/hip_runtime.h>
#include <hip/hip_bf16.h>

#define N_Q 256
#define M_S 1024
#define DD 512
#define HH 512

typedef __attribute__((ext_vector_type(8))) short short8;
typedef __attribute__((ext_vector_type(8))) __bf16 bf16x8;
typedef __attribute__((ext_vector_type(16))) float f32x16;
typedef __attribute__((ext_vector_type(2))) __bf16 bf16x2;

union U8 { short8 s; bf16x8 b; };

__device__ __forceinline__ unsigned short f2bf(float f) {
  unsigned int u = __float_as_uint(f);
  u += 0x7FFFu + ((u >> 16) & 1u);
  return (unsigned short)(u >> 16);
}

__device__ __forceinline__ short8 pack8(const float* d) {
#if defined(__has_builtin) && __has_builtin(__builtin_amdgcn_cvt_pk_bf16_f32)
  short8 r;
#pragma unroll
  for (int i = 0; i < 4; ++i) {
    union { bf16x2 v; short s[2]; } u;
    u.v = __builtin_amdgcn_cvt_pk_bf16_f32(d[2 * i], d[2 * i + 1]);
    r[2 * i] = u.s[0];
    r[2 * i + 1] = u.s[1];
  }
  return r;
#else
  short8 r;
#pragma unroll
  for (int i = 0; i < 8; ++i) r[i] = (short)f2bf(d[i]);
  return r;
#endif
}

__device__ __forceinline__ short8 packdiff(float4 e0, float4 e1, float4 s0, float4 s1) {
  float d[8];
  d[0] = fabsf(e0.x - s0.x); d[1] = fabsf(e0.y - s0.y);
  d[2] = fabsf(e0.z - s0.z); d[3] = fabsf(e0.w - s0.w);
  d[4] = fabsf(e1.x - s1.x); d[5] = fabsf(e1.y - s1.y);
  d[6] = fabsf(e1.z - s1.z); d[7] = fabsf(e1.w - s1.w);
  return pack8(d);
}

// async global->LDS DMA, 16 B/lane: LDS dest = uniform base + lane*16.
__device__ __forceinline__ void dma16(const void* g, void* l) {
  __builtin_amdgcn_global_load_lds(
      (const __attribute__((address_space(1))) unsigned int*)g,
      (__attribute__((address_space(3))) unsigned int*)l, 16, 0, 0);
}

// W1 [D][H] fp32 -> w1s in MFMA-B-fragment order (verified R3-R12), LDS-transposed.
// Frag f = kc*16 + h32 is 1024 contiguous bytes; lane l owns bytes [l*16, l*16+16).
__global__ __launch_bounds__(512) void prep_w1s(const float* __restrict__ W1,
                                                unsigned short* __restrict__ w1s) {
  __shared__ float tile[16 * 516];
  const int t = threadIdx.x;
  const int kc = blockIdx.x;         // 0..31
  const float* src = W1 + kc * 16 * HH;
#pragma unroll
  for (int pass = 0; pass < 4; ++pass) {
    const int fi = pass * 2048 + t * 4;
    const float4 v = *(const float4*)(src + fi);
    *(float4*)&tile[(fi >> 9) * 516 + (fi & 511)] = v;
  }
  __syncthreads();
  const int l = t & 63, h32g = t >> 6;
  const int l31 = l & 31, kh = l >> 5;
#pragma unroll
  for (int i = 0; i < 2; ++i) {
    const int h32 = i * 8 + h32g;
    short8 v;
#pragma unroll
    for (int j = 0; j < 8; ++j)
      v[j] = (short)f2bf(tile[(kh * 8 + j) * 516 + h32 * 32 + l31]);
    *(short8*)(w1s + (kc * 16 + h32) * 512 + l * 8) = v;
  }
}

// R13: async-DMA B ring. Block 512 thr = 8 waves, tile 64p x 512h x K=512.
// A: 64p x 128k quarter tiles in 16 KB LDS (restaged 4x, [p][c^(p&7)] XOR).
// B: wave-private LDS ring, 3 slots x 1 ks x 2 frags (6 KB/wave, 48 KB total),
// filled by global_load_lds (no VGPR dest -> compiler cannot sink it),
// distance-2 prefetch enforced by manual s_waitcnt vmcnt(N) (in-order
// retirement => conservative-safe even with interleaved staging loads).
// Wave 64p x 64h -> acc[2][2] = 64 AGPR.
__global__ __launch_bounds__(512, 4) void support_kernel(
    const float* __restrict__ emb, const float* __restrict__ sup,
    const unsigned short* __restrict__ w1s, const float* __restrict__ b1,
    const float* __restrict__ W2, const float* __restrict__ b2,
    float* __restrict__ out) {
  __shared__ short8 As16[64 * 16];        // 16 KB: A quarter [p][c' 0..15]
  __shared__ short8 Bring[8][3][2][64];   // 48 KB: [wid][slot][tj][lane]

  const int tid = threadIdx.x;
  const int lane = tid & 63;
  const int wid = tid >> 6;               // 0..7 : 64-h slice
  const int l31 = lane & 31;
  const int khalf = lane >> 5;
  const int ax = l31 & 7;

  const int m0 = blockIdx.x * 16;
  const int n0 = blockIdx.y * 4;

  // staging map: c = 16B k-chunk (0..15), rw = tid>>4 -> 2 pair rows each
  const int c = tid & 15;
  const int rw = tid >> 4;

  // ---- prologue: DMA B for ks=0,1 (ages through staging) ----
#pragma unroll
  for (int pk = 0; pk < 2; ++pk)
#pragma unroll
    for (int tj = 0; tj < 2; ++tj)
      dma16(w1s + (pk * 16 + wid * 2 + tj) * 512 + lane * 8,
            &Bring[wid][pk][tj][0]);

  f32x16 acc[2][2] = {};
  U8 a[2][2];

#pragma unroll
  for (int q = 0; q < 4; ++q) {
    if (q) __syncthreads();               // prior quarter's A reads done
    // ---- stage A quarter q: 64p x 128k ----
#pragma unroll
    for (int r = 0; r < 2; ++r) {
      const int p = rw * 2 + r;
      const float* ep = emb + (n0 + (p >> 4)) * DD + q * 128 + c * 8;
      const float* sp = sup + (m0 + (p & 15)) * DD + q * 128 + c * 8;
      const float4 e0 = *(const float4*)ep;
      const float4 e1 = *(const float4*)(ep + 4);
      const float4 s0 = *(const float4*)sp;
      const float4 s1 = *(const float4*)(sp + 4);
      As16[p * 16 + (c ^ (p & 7))] = packdiff(e0, e1, s0, s1);
    }
    __syncthreads();                      // A visible (drains vmcnt too; DMAs are old)

    // A prologue for j=0 of this quarter
    a[0][0].s = As16[l31 * 16 + (khalf ^ ax)];
    a[0][1].s = As16[(32 + l31) * 16 + (khalf ^ ax)];

#pragma unroll
    for (int j = 0; j < 8; ++j) {
      const int ks = q * 8 + j;
      const int cur = j & 1;
      // issue DMA for ks+2 (slot (ks+2)%3 differs from live ks, ks+1 slots)
      if (ks + 2 < 32) {
#pragma unroll
        for (int tj = 0; tj < 2; ++tj)
          dma16(w1s + ((ks + 2) * 16 + wid * 2 + tj) * 512 + lane * 8,
                &Bring[wid][(ks + 2) % 3][tj][0]);
      }
      // wait until ks's 2 DMAs retired: keep only the newer prefetches.
      // vmcnt retires in issue order -> over-waits (never under-waits) if the
      // compiler interleaved other vmem after our DMAs.
      if (ks + 2 < 32)      __builtin_amdgcn_s_waitcnt(0xF74);  // vmcnt<=4
      else if (ks + 1 < 32) __builtin_amdgcn_s_waitcnt(0xF72);  // vmcnt<=2
      else                  __builtin_amdgcn_s_waitcnt(0xF70);  // vmcnt<=0
      // B frags from the ring (this wave's private slots)
      U8 b0, b1f;
      b0.s = Bring[wid][ks % 3][0][lane];
      b1f.s = Bring[wid][ks % 3][1][lane];
      // A lookahead depth 1 (LDS)
      if (j < 7) {
        const int cc = ((j + 1) * 2 + khalf) ^ ax;
        a[cur ^ 1][0].s = As16[l31 * 16 + cc];
        a[cur ^ 1][1].s = As16[(32 + l31) * 16 + cc];
      }
#pragma unroll
      for (int am = 0; am < 2; ++am) {
        acc[am][0] = __builtin_amdgcn_mfma_f32_32x32x16_bf16(
            a[cur][am].b, b0.b, acc[am][0], 0, 0, 0);
        acc[am][1] = __builtin_amdgcn_mfma_f32_32x32x16_bf16(
            a[cur][am].b, b1f.b, acc[am][1], 0, 0, 0);
      }
    }
  }

  // ---- epilogue (R8-proven): s = sum_{64 h} relu(C+b1)*W2; psums reduce ----
  float b1v[2], w2v[2];
#pragma unroll
  for (int tj = 0; tj < 2; ++tj) {
    const int h = (wid * 2 + tj) * 32 + l31;   // C/D: col = lane&31
    b1v[tj] = b1[h];
    w2v[tj] = W2[h];
  }
  __syncthreads();                             // all As16 reads done
  float* psums = (float*)As16;                 // [64 pairs][8 waves] = 2 KB
#pragma unroll
  for (int am = 0; am < 2; ++am) {
#pragma unroll
    for (int r = 0; r < 16; ++r) {
      float s = fmaxf(acc[am][0][r] + b1v[0], 0.f) * w2v[0] +
                fmaxf(acc[am][1][r] + b1v[1], 0.f) * w2v[1];
      s += __shfl_xor(s, 1, 64);
      s += __shfl_xor(s, 2, 64);
      s += __shfl_xor(s, 4, 64);
      s += __shfl_xor(s, 8, 64);
      s += __shfl_xor(s, 16, 64);
      if (l31 == 0) {
        const int row32 = (r & 3) + 8 * (r >> 2) + 4 * khalf;  // C/D row map
        psums[(am * 32 + row32) * 8 + wid] = s;
      }
    }
  }
  __syncthreads();
  if (tid < 64) {
    float t = b2[0];
#pragma unroll
    for (int w = 0; w < 8; ++w) t += psums[tid * 8 + w];
    out[(n0 + (tid >> 4)) * M_S + m0 + (tid & 15)] = 1.f / (1.f + __expf(-t));
  }
}

extern "C" void kernel_launch(void* const* d_in, const int* in_sizes, int n_in,
                              void* d_out, int out_size, void* d_ws, size_t ws_size,
                              hipStream_t stream) {
  const float* emb = (const float*)d_in[0];
  const float* sup = (const float*)d_in[1];
  const float* W1  = (const float*)d_in[2];
  const float* b1  = (const float*)d_in[3];
  const float* W2  = (const float*)d_in[4];
  const float* b2  = (const float*)d_in[5];
  float* out = (float*)d_out;
  unsigned short* w1s = (unsigned short*)d_ws;  // 512 KB fragment-ordered W1

  prep_w1s<<<32, 512, 0, stream>>>(W1, w1s);
  support_kernel<<<dim3(M_S / 16, N_Q / 4), 512, 0, stream>>>(
      emb, sup, w1s, b1, W2, b2, out);
}